// Round 19
// baseline (79.680 us; speedup 1.0000x reference)
//
#include <hip/hip_runtime.h>

typedef unsigned short u16;
typedef unsigned long long u64;
typedef __attribute__((ext_vector_type(8))) short s16x8;
typedef __attribute__((ext_vector_type(4))) float f32x4;

#define MFMA16(a, b, c) __builtin_amdgcn_mfma_f32_16x16x32_bf16((a), (b), (c), 0, 0, 0)

// round-to-nearest-even f32 -> bf16 (raw u16)
__device__ __forceinline__ u16 f2bf(float f) {
  unsigned u = __float_as_uint(f);
  u += 0x7fffu + ((u >> 16) & 1u);
  return (u16)(u >> 16);
}

// async global->LDS, 16B per lane, wave-uniform LDS base (+lane*16 by HW)
__device__ __forceinline__ void gld_lds16(const void* g, void* l) {
  __builtin_amdgcn_global_load_lds(
      (const __attribute__((address_space(1))) void*)g,
      (__attribute__((address_space(3))) void*)l, 16, 0, 0);
}

// ---------------------------------------------------------------------------
// prep (weights only now): blocks [0,384) wqkv transpose+cast (PERM);
// [384,512) wproj transpose+cast.  xcast is gone — gemm1 converts X inline.
// ---------------------------------------------------------------------------
__global__ __launch_bounds__(256) void prep(const float* __restrict__ Wqkv,
                                            const float* __restrict__ Wproj,
                                            u16* __restrict__ wqT,
                                            u16* __restrict__ wpT) {
  const int bid = blockIdx.x;
  if (bid < 384) {
    int idx = bid * 256 + threadIdx.x;
    int n = idx % 1536;
    int kc = idx / 1536;
    int t = n >> 9, ct = n & 511, h = ct >> 6, d = ct & 63;
    int src_c = h * 192 + t * 64 + d;
    s16x8 hv;
#pragma unroll
    for (int i = 0; i < 8; ++i) hv[i] = (short)f2bf(Wqkv[(size_t)(kc * 8 + i) * 1536 + src_c]);
    *(s16x8*)(wqT + (size_t)n * 512 + (size_t)kc * 8) = hv;
  } else {
    int idx = (bid - 384) * 256 + threadIdx.x;
    int n = idx % 512;
    int kc = idx / 512;
    s16x8 hv;
#pragma unroll
    for (int i = 0; i < 8; ++i) hv[i] = (short)f2bf(Wproj[(size_t)(kc * 8 + i) * 512 + n]);
    *(s16x8*)(wpT + (size_t)n * 512 + (size_t)kc * 8) = hv;
  }
}

// ---------------------------------------------------------------------------
// 128x128 bf16 GEMM, BK=64, DOUBLE-buffered (64 KB LDS), T4 pipeline + T5.
// EPI=1 (gemm1): A reg-staged DIRECTLY from X f32 (T14 split: loads issued
//   before compute(t), convert+swizzled ds_write after) — kills the Xb
//   round-trip. B via gld_lds from wqT. Epilogue: qkv scatter + v-transpose.
// EPI=0 (gemm2): A and B via gld_lds (R17 path, unchanged).
// ---------------------------------------------------------------------------
template <int EPI, int NCOL>
__global__ __launch_bounds__(256, 2) void gemm_bf16(
    const float* __restrict__ Xf,                     // EPI=1 only
    const u16* __restrict__ A, const u16* __restrict__ B,
    float* __restrict__ OUT,
    u16* __restrict__ qo, u16* __restrict__ ko, u16* __restrict__ vto) {
  __shared__ u16 LDS[32768];  // 64 KB: SA[2][128][64] | SB[2][128][64]
  u16* SA = LDS;              // buf stride 8192 u16
  u16* SB = LDS + 16384;
  const int tid = threadIdx.x;
  const int w = tid >> 6, lane = tid & 63;
  const int l15 = lane & 15, l4 = lane >> 4;
  const int bid0 = blockIdx.x;
  const int work = (bid0 & 7) * (8 * NCOL) + (bid0 >> 3);
  const int bx = work / NCOL;
  const int by = work % NCOL;
  const int row0 = bx * 128;
  const int col0 = by * 128;
  const int wr = w >> 1, wc = w & 1;

  const int lrow = lane >> 3, lslot = lane & 7;
  const int srcoff = lrow * 1024 + ((lslot ^ lrow) << 4);  // bytes
  const char* pA = (const char*)A + (size_t)(row0 + w * 32) * 1024 + srcoff;
  const char* pB = (const char*)B + (size_t)(col0 + w * 32) * 1024 + srcoff;
  u16* sAw = SA + (w * 32) * 64;
  u16* sBw = SB + (w * 32) * 64;

  // EPI=1 A-source: lane covers row w*32+(lane>>1), k-half (lane&1)*32
  const int arow = w * 32 + (lane >> 1);
  const int ahalf = (lane & 1) * 32;
  const float* pAf = Xf + (size_t)(row0 + arow) * 512 + ahalf;

#define STAGE_B(t_, b_)                                             \
  do {                                                              \
    const int kbb = (t_)*128;                                       \
    _Pragma("unroll")                                               \
    for (int j = 0; j < 4; ++j)                                     \
      gld_lds16(pB + j * 8192 + kbb, sBw + (b_)*8192 + j * 512);    \
  } while (0)

#define STAGE_A(t_, b_)                                             \
  do {                                                              \
    const int kbb = (t_)*128;                                       \
    _Pragma("unroll")                                               \
    for (int j = 0; j < 4; ++j)                                     \
      gld_lds16(pA + j * 8192 + kbb, sAw + (b_)*8192 + j * 512);    \
  } while (0)

  // EPI=1: convert 32 in-flight floats and write swizzled 16B slots
  float4 a_in[8];
#define LOAD_AF(t_)                                                 \
  do {                                                              \
    _Pragma("unroll")                                               \
    for (int j = 0; j < 8; ++j)                                     \
      a_in[j] = *(const float4*)(pAf + (t_)*64 + j * 4);            \
  } while (0)

#define CONV_AF(b_)                                                 \
  do {                                                              \
    _Pragma("unroll")                                               \
    for (int j2 = 0; j2 < 4; ++j2) {                                \
      uint4 pk;                                                     \
      pk.x = (unsigned)f2bf(a_in[j2 * 2].x) | ((unsigned)f2bf(a_in[j2 * 2].y) << 16);   \
      pk.y = (unsigned)f2bf(a_in[j2 * 2].z) | ((unsigned)f2bf(a_in[j2 * 2].w) << 16);   \
      pk.z = (unsigned)f2bf(a_in[j2 * 2 + 1].x) | ((unsigned)f2bf(a_in[j2 * 2 + 1].y) << 16); \
      pk.w = (unsigned)f2bf(a_in[j2 * 2 + 1].z) | ((unsigned)f2bf(a_in[j2 * 2 + 1].w) << 16); \
      const int s = ((ahalf >> 3) + j2) ^ (arow & 7);               \
      *(uint4*)&SA[(b_)*8192 + arow * 64 + s * 8] = pk;             \
    }                                                               \
  } while (0)

  const f32x4 fz = {0.f, 0.f, 0.f, 0.f};
  f32x4 acc[4][4];
  for (int a = 0; a < 4; ++a)
    for (int b = 0; b < 4; ++b) acc[a][b] = fz;

  // prologue
  if (EPI == 1) {
    LOAD_AF(0);
    STAGE_B(0, 0);
    asm volatile("s_waitcnt vmcnt(0)" ::: "memory");
    __builtin_amdgcn_sched_barrier(0);
    CONV_AF(0);
    asm volatile("s_waitcnt lgkmcnt(0)" ::: "memory");
    __builtin_amdgcn_sched_barrier(0);
    __builtin_amdgcn_s_barrier();
  } else {
    STAGE_A(0, 0);
    STAGE_B(0, 0);
    asm volatile("s_waitcnt vmcnt(0)" ::: "memory");
    __builtin_amdgcn_sched_barrier(0);
    __builtin_amdgcn_s_barrier();
  }

  for (int t = 0; t < 8; ++t) {
    const int cur = t & 1;
    if (t + 1 < 8) {
      if (EPI == 1) {
        LOAD_AF(t + 1);           // f32 loads fly under compute(t)
        STAGE_B(t + 1, cur ^ 1);
      } else {
        STAGE_A(t + 1, cur ^ 1);
        STAGE_B(t + 1, cur ^ 1);
      }
      __builtin_amdgcn_sched_barrier(0);
    }
#pragma unroll
    for (int ks = 0; ks < 2; ++ks) {
      s16x8 af[4], bf[4];
#pragma unroll
      for (int mi = 0; mi < 4; ++mi) {
        const int r = wr * 64 + mi * 16 + l15;
        const int sl = (ks * 4 + l4) ^ (r & 7);
        af[mi] = *(const s16x8*)&SA[cur * 8192 + r * 64 + sl * 8];
      }
#pragma unroll
      for (int nj = 0; nj < 4; ++nj) {
        const int r = wc * 64 + nj * 16 + l15;
        const int sl = (ks * 4 + l4) ^ (r & 7);
        bf[nj] = *(const s16x8*)&SB[cur * 8192 + r * 64 + sl * 8];
      }
      __builtin_amdgcn_s_setprio(1);
#pragma unroll
      for (int nj = 0; nj < 4; ++nj)
#pragma unroll
        for (int mi = 0; mi < 4; ++mi) acc[mi][nj] = MFMA16(af[mi], bf[nj], acc[mi][nj]);
      __builtin_amdgcn_s_setprio(0);
    }
    if (t < 7) {
      asm volatile("s_waitcnt vmcnt(0)" ::: "memory");  // A-regs + B-LDS landed
      __builtin_amdgcn_sched_barrier(0);
      if (EPI == 1) {
        CONV_AF(cur ^ 1);                               // write A(t+1) swizzled
        asm volatile("s_waitcnt lgkmcnt(0)" ::: "memory");
        __builtin_amdgcn_sched_barrier(0);
      }
      __builtin_amdgcn_s_barrier();
    }
  }
#undef STAGE_A
#undef STAGE_B
#undef LOAD_AF
#undef CONV_AF

  if (EPI == 0) {
#pragma unroll
    for (int mi = 0; mi < 4; ++mi)
#pragma unroll
      for (int nj = 0; nj < 4; ++nj)
#pragma unroll
        for (int rg = 0; rg < 4; ++rg) {
          int r_g = row0 + wr * 64 + mi * 16 + l4 * 4 + rg;
          int c_g = col0 + wc * 64 + nj * 16 + l15;
          OUT[(size_t)r_g * 512 + c_g] = acc[mi][nj][rg];
        }
    return;
  }

  // ---- gemm1 epilogue ----
  const int b = row0 >> 11, srow = row0 & 2047;
  if (by < 8) {
    const int isq = (by < 4);
    const float QS = 0.06375874f;  // 512^-0.5 * log2(e)
    u16* dst = isq ? qo : ko;
#pragma unroll
    for (int mi = 0; mi < 4; ++mi)
#pragma unroll
      for (int nj = 0; nj < 4; ++nj)
#pragma unroll
        for (int rg = 0; rg < 4; ++rg) {
          float v = acc[mi][nj][rg];
          if (isq) v *= QS;
          int s = srow + wr * 64 + mi * 16 + l4 * 4 + rg;
          int ct = ((by & 3) * 128 + wc * 64 + nj * 16 + l15);
          int h = ct >> 6, d = ct & 63;
          dst[(((size_t)b * 8 + h) * 2048 + s) * 64 + d] = f2bf(v);
        }
  } else {
    // v: transpose in TWO 64-col passes (pitch 130), reusing K-loop LDS
    const int vb = by - 8;
#pragma unroll
    for (int h = 0; h < 2; ++h) {
      __syncthreads();
      if (wc == h) {
#pragma unroll
        for (int mi = 0; mi < 4; ++mi)
#pragma unroll
          for (int nj = 0; nj < 4; ++nj)
#pragma unroll
            for (int rg = 0; rg < 4; ++rg) {
              int cl = nj * 16 + l15;
              int s = wr * 64 + mi * 16 + l4 * 4 + rg;
              LDS[cl * 130 + s] = f2bf(acc[mi][nj][rg]);
            }
      }
      __syncthreads();
      const unsigned* LDSw = (const unsigned*)LDS;
      int cl = tid >> 2, sh = tid & 3;
      int ct = vb * 128 + h * 64 + cl;
      int hd = ct >> 6, d = ct & 63;
      size_t o = (((size_t)b * 8 + hd) * 64 + d) * 2048 + srow + sh * 32;
      unsigned wbuf[16];
#pragma unroll
      for (int p = 0; p < 16; ++p) wbuf[p] = LDSw[cl * 65 + sh * 16 + p];
#pragma unroll
      for (int j = 0; j < 4; ++j) {
        uint4 u = {wbuf[j * 4], wbuf[j * 4 + 1], wbuf[j * 4 + 2], wbuf[j * 4 + 3]};
        *(uint4*)(vto + o + j * 8) = u;
      }
    }
  }
}

// ---------------------------------------------------------------------------
// Banded flash attention — R18 version (T4 + swapped QK^T + T5), unchanged.
// ---------------------------------------------------------------------------
__global__ __launch_bounds__(512, 4) void attn_kernel(
    const u16* __restrict__ q, const u16* __restrict__ k,
    const u16* __restrict__ vt, u16* __restrict__ ao) {
  __shared__ u16 KT[3][64 * 64];      // 24 KB
  __shared__ u16 VT[3][64 * 64];      // 24 KB
  __shared__ u16 PT[8][16 * 64];      // 16 KB   PT[w][q][key^swz]
  const int tid = threadIdx.x;
  const int w = tid >> 6, lane = tid & 63;
  const int l15 = lane & 15, l4 = lane >> 4;
  const int bid0 = blockIdx.x;
  const int bid = (bid0 & 7) * 64 + (bid0 >> 3);  // XCD remap (512 % 8 == 0)
  const int qt = bid & 15, hh = (bid >> 4) & 7, b = bid >> 7;
  const size_t base = (size_t)(b * 8 + hh) * 2048 * 64;
  const int q0 = qt * 128 + w * 16;

  s16x8 qf[2];
#pragma unroll
  for (int ks = 0; ks < 2; ++ks)
    qf[ks] = *(const s16x8*)(q + base + (size_t)(q0 + l15) * 64 + ks * 32 + l4 * 8);

  const f32x4 fz = {0.f, 0.f, 0.f, 0.f};
  f32x4 O[4];
  for (int nd = 0; nd < 4; ++nd) O[nd] = fz;
  float l_sum = 0.f;

  const int lrow = lane >> 3, lslot = lane & 7;
  const int swzb = (lslot ^ lrow) << 4;
  const char* pK = (const char*)(k + base) + (w * 8 + lrow) * 128 + swzb;
  const char* pV = (const char*)(vt + base) + (size_t)(w * 8 + lrow) * 4096 + swzb;
  u16* dK = &KT[0][0] + w * 512;
  u16* dV = &VT[0][0] + w * 512;
  u16* phw = &PT[w][0];
  const int pswz = (l15 & 7) << 3;

#define STAGE(c_, b_)                                    \
  do {                                                   \
    gld_lds16(pK + (c_) * 8192, dK + (b_) * 4096);       \
    gld_lds16(pV + (c_) * 128,  dV + (b_) * 4096);       \
  } while (0)

  const int c0 = (2 * qt - 2) < 0 ? 0 : (2 * qt - 2);
  const int c1 = (2 * qt + 3) > 31 ? 31 : (2 * qt + 3);

  STAGE(c0, 0);
  STAGE(c0 + 1, 1);
  asm volatile("s_waitcnt vmcnt(2)" ::: "memory");
  __builtin_amdgcn_sched_barrier(0);
  __builtin_amdgcn_s_barrier();

  for (int c = c0; c <= c1; ++c) {
    const int buf = (c - c0) % 3;
    if (c + 2 <= c1) STAGE(c + 2, (c - c0 + 2) % 3);
    const int kb = c * 64;
    const bool skip = (kb - (q0 + 15) > 128) || (q0 - (kb + 63) > 128);
    if (!skip) {
      f32x4 S[4];
      for (int nj = 0; nj < 4; ++nj) S[nj] = fz;
      __builtin_amdgcn_s_setprio(1);
#pragma unroll
      for (int nj = 0; nj < 4; ++nj) {
        const int r = nj * 16 + l15;
#pragma unroll
        for (int ks = 0; ks < 2; ++ks) {
          const int sl = (ks * 4 + l4) ^ (r & 7);
          s16x8 kf = *(const s16x8*)&KT[buf][r * 64 + sl * 8];
          S[nj] = MFMA16(kf, qf[ks], S[nj]);
        }
      }
      __builtin_amdgcn_s_setprio(0);
      const bool needmask = (kb + 63 - q0 > 128) || (q0 + 15 - kb > 128);
      const int qrow = q0 + l15;
#pragma unroll
      for (int nj = 0; nj < 4; ++nj) {
        float p[4];
#pragma unroll
        for (int rg = 0; rg < 4; ++rg) {
          const int key = kb + nj * 16 + l4 * 4 + rg;
          float pp = exp2f(S[nj][rg]);
          if (needmask) {
            int dd = key - qrow;
            if (dd > 128 || dd < -128) pp = 0.f;
          }
          l_sum += pp;
          p[rg] = pp;
        }
        unsigned w0 = (unsigned)f2bf(p[0]) | ((unsigned)f2bf(p[1]) << 16);
        unsigned w1 = (unsigned)f2bf(p[2]) | ((unsigned)f2bf(p[3]) << 16);
        u64 pk = ((u64)w1 << 32) | (u64)w0;
        const int kbase = (nj * 16 + l4 * 4) ^ pswz;
        *(u64*)&phw[l15 * 64 + kbase] = pk;
      }
      __builtin_amdgcn_s_setprio(1);
#pragma unroll
      for (int ksp = 0; ksp < 2; ++ksp) {
        const int kbase = (ksp * 32 + l4 * 8) ^ pswz;
        s16x8 pa = *(const s16x8*)&phw[l15 * 64 + kbase];
#pragma unroll
        for (int nd = 0; nd < 4; ++nd) {
          const int r = nd * 16 + l15;
          const int sl = (ksp * 4 + l4) ^ (r & 7);
          s16x8 vf = *(const s16x8*)&VT[buf][r * 64 + sl * 8];
          O[nd] = MFMA16(pa, vf, O[nd]);
        }
      }
      __builtin_amdgcn_s_setprio(0);
    }
    if (c < c1) {
      if (c + 2 <= c1) {
        asm volatile("s_waitcnt vmcnt(2)" ::: "memory");
      } else {
        asm volatile("s_waitcnt vmcnt(0)" ::: "memory");
      }
      __builtin_amdgcn_sched_barrier(0);
      __builtin_amdgcn_s_barrier();
    }
  }
#undef STAGE

  l_sum += __shfl_xor(l_sum, 16);
  l_sum += __shfl_xor(l_sum, 32);
  float linv = 1.0f / l_sum;
#pragma unroll
  for (int rg = 0; rg < 4; ++rg) {
    const float inv = __shfl(linv, l4 * 4 + rg);
    const int s_g = q0 + l4 * 4 + rg;
#pragma unroll
    for (int nd = 0; nd < 4; ++nd) {
      float v = O[nd][rg] * inv;
      const int c_g = hh * 64 + nd * 16 + l15;
      ao[((size_t)b * 2048 + s_g) * 512 + c_g] = f2bf(v);
    }
  }
}

// ---------------------------------------------------------------------------
extern "C" void kernel_launch(void* const* d_in, const int* in_sizes, int n_in,
                              void* d_out, int out_size, void* d_ws, size_t ws_size,
                              hipStream_t stream) {
  const float* x = (const float*)d_in[0];      // [4,2048,512]
  const float* wqkv = (const float*)d_in[1];   // [512,1536]
  const float* wproj = (const float*)d_in[2];  // [512,512]
  float* out = (float*)d_out;                  // [4,2048,512]

  char* ws = (char*)d_ws;
  size_t off = 0;
  auto alloc = [&](size_t bytes) {
    void* p = ws + off;
    off += (bytes + 255) & ~(size_t)255;
    return p;
  };
  const size_t E = (size_t)4 * 8 * 2048 * 64;
  u16* qb  = (u16*)alloc(E * 2);
  u16* kb  = (u16*)alloc(E * 2);
  u16* vtb = (u16*)alloc(E * 2);
  u16* aob = (u16*)alloc(E * 2);
  u16* wqT = (u16*)alloc((size_t)1536 * 512 * 2);
  u16* wpT = (u16*)alloc((size_t)512 * 512 * 2);

  prep<<<dim3(512), dim3(256), 0, stream>>>(wqkv, wproj, wqT, wpT);
  gemm_bf16<1, 12><<<dim3(768), dim3(256), 0, stream>>>(x, nullptr, wqT, nullptr, qb, kb, vtb);
  attn_kernel<<<dim3(512), dim3(512), 0, stream>>>(qb, kb, vtb, aob);
  gemm_bf16<0, 4><<<dim3(256), dim3(256), 0, stream>>>(nullptr, aob, wpT, out, nullptr, nullptr, nullptr);
}

// Round 20
// 58.728 us; speedup vs baseline: 1.3568x; 1.3568x over previous
//
#include <hip/hip_runtime.h>

typedef unsigned short u16;
typedef unsigned long long u64;
typedef __attribute__((ext_vector_type(8))) short s16x8;
typedef __attribute__((ext_vector_type(4))) float f32x4;

#define MFMA16(a, b, c) __builtin_amdgcn_mfma_f32_16x16x32_bf16((a), (b), (c), 0, 0, 0)

// round-to-nearest-even f32 -> bf16 (raw u16)
__device__ __forceinline__ u16 f2bf(float f) {
  unsigned u = __float_as_uint(f);
  u += 0x7fffu + ((u >> 16) & 1u);
  return (u16)(u >> 16);
}

// async global->LDS, 16B per lane, wave-uniform LDS base (+lane*16 by HW)
__device__ __forceinline__ void gld_lds16(const void* g, void* l) {
  __builtin_amdgcn_global_load_lds(
      (const __attribute__((address_space(1))) void*)g,
      (__attribute__((address_space(3))) void*)l, 16, 0, 0);
}

// ---------------------------------------------------------------------------
// Fused prep: blocks [0,2048) xcast; [2048,2432) wqkv transpose+cast (PERM);
// [2432,2560) wproj transpose+cast.
// ---------------------------------------------------------------------------
__global__ __launch_bounds__(256) void prep(const float* __restrict__ X,
                                            const float* __restrict__ Wqkv,
                                            const float* __restrict__ Wproj,
                                            u16* __restrict__ Xb,
                                            u16* __restrict__ wqT,
                                            u16* __restrict__ wpT) {
  const int bid = blockIdx.x;
  if (bid < 2048) {
    size_t idx = (size_t)bid * 256 + threadIdx.x;
    const float4 f0 = *(const float4*)(X + idx * 8);
    const float4 f1 = *(const float4*)(X + idx * 8 + 4);
    float fs[8] = {f0.x, f0.y, f0.z, f0.w, f1.x, f1.y, f1.z, f1.w};
    s16x8 hv;
#pragma unroll
    for (int j = 0; j < 8; ++j) hv[j] = (short)f2bf(fs[j]);
    *(s16x8*)(Xb + idx * 8) = hv;
  } else if (bid < 2432) {
    int idx = (bid - 2048) * 256 + threadIdx.x;
    int n = idx % 1536;
    int kc = idx / 1536;
    int t = n >> 9, ct = n & 511, h = ct >> 6, d = ct & 63;
    int src_c = h * 192 + t * 64 + d;
    s16x8 hv;
#pragma unroll
    for (int i = 0; i < 8; ++i) hv[i] = (short)f2bf(Wqkv[(size_t)(kc * 8 + i) * 1536 + src_c]);
    *(s16x8*)(wqT + (size_t)n * 512 + (size_t)kc * 8) = hv;
  } else {
    int idx = (bid - 2432) * 256 + threadIdx.x;
    int n = idx % 512;
    int kc = idx / 512;
    s16x8 hv;
#pragma unroll
    for (int i = 0; i < 8; ++i) hv[i] = (short)f2bf(Wproj[(size_t)(kc * 8 + i) * 512 + n]);
    *(s16x8*)(wpT + (size_t)n * 512 + (size_t)kc * 8) = hv;
  }
}

// ---------------------------------------------------------------------------
// 128x128 bf16 GEMM, BK=64, DOUBLE-buffered (64 KB LDS exactly), T4 pipeline,
// T5 setprio. R17/R18 version, unchanged.
// ---------------------------------------------------------------------------
template <int EPI, int NCOL>
__global__ __launch_bounds__(256, 2) void gemm_bf16(
    const u16* __restrict__ A, const u16* __restrict__ B,
    float* __restrict__ OUT,
    u16* __restrict__ qo, u16* __restrict__ ko, u16* __restrict__ vto) {
  __shared__ u16 LDS[32768];  // 64 KB exactly: SA[2][128][64] | SB[2][128][64]
  u16* SA = LDS;              // buf stride 8192 u16
  u16* SB = LDS + 16384;
  const int tid = threadIdx.x;
  const int w = tid >> 6, lane = tid & 63;
  const int l15 = lane & 15, l4 = lane >> 4;
  const int bid0 = blockIdx.x;
  const int work = (bid0 & 7) * (8 * NCOL) + (bid0 >> 3);
  const int bx = work / NCOL;
  const int by = work % NCOL;
  const int row0 = bx * 128;
  const int col0 = by * 128;
  const int wr = w >> 1, wc = w & 1;

  const int lrow = lane >> 3, lslot = lane & 7;
  const int srcoff = lrow * 1024 + ((lslot ^ lrow) << 4);  // bytes
  const char* pA = (const char*)A + (size_t)(row0 + w * 32) * 1024 + srcoff;
  const char* pB = (const char*)B + (size_t)(col0 + w * 32) * 1024 + srcoff;
  u16* sAw = SA + (w * 32) * 64;
  u16* sBw = SB + (w * 32) * 64;

#define STAGE(t_, b_)                                               \
  do {                                                              \
    const int kbb = (t_)*128;                                       \
    _Pragma("unroll")                                               \
    for (int j = 0; j < 4; ++j) {                                   \
      gld_lds16(pA + j * 8192 + kbb, sAw + (b_)*8192 + j * 512);    \
      gld_lds16(pB + j * 8192 + kbb, sBw + (b_)*8192 + j * 512);    \
    }                                                               \
  } while (0)

  const f32x4 fz = {0.f, 0.f, 0.f, 0.f};
  f32x4 acc[4][4];
  for (int a = 0; a < 4; ++a)
    for (int b = 0; b < 4; ++b) acc[a][b] = fz;

  STAGE(0, 0);
  asm volatile("s_waitcnt vmcnt(0)" ::: "memory");
  __builtin_amdgcn_sched_barrier(0);
  __builtin_amdgcn_s_barrier();

  for (int t = 0; t < 8; ++t) {
    const int cur = t & 1;
    if (t + 1 < 8) STAGE(t + 1, cur ^ 1);
#pragma unroll
    for (int ks = 0; ks < 2; ++ks) {
      s16x8 af[4], bf[4];
#pragma unroll
      for (int mi = 0; mi < 4; ++mi) {
        const int r = wr * 64 + mi * 16 + l15;
        const int sl = (ks * 4 + l4) ^ (r & 7);
        af[mi] = *(const s16x8*)&SA[cur * 8192 + r * 64 + sl * 8];
      }
#pragma unroll
      for (int nj = 0; nj < 4; ++nj) {
        const int r = wc * 64 + nj * 16 + l15;
        const int sl = (ks * 4 + l4) ^ (r & 7);
        bf[nj] = *(const s16x8*)&SB[cur * 8192 + r * 64 + sl * 8];
      }
      __builtin_amdgcn_s_setprio(1);
#pragma unroll
      for (int nj = 0; nj < 4; ++nj)
#pragma unroll
        for (int mi = 0; mi < 4; ++mi) acc[mi][nj] = MFMA16(af[mi], bf[nj], acc[mi][nj]);
      __builtin_amdgcn_s_setprio(0);
    }
    if (t < 7) {
      asm volatile("s_waitcnt vmcnt(0)" ::: "memory");
      __builtin_amdgcn_sched_barrier(0);
      __builtin_amdgcn_s_barrier();
    }
  }
#undef STAGE

  if (EPI == 0) {
#pragma unroll
    for (int mi = 0; mi < 4; ++mi)
#pragma unroll
      for (int nj = 0; nj < 4; ++nj)
#pragma unroll
        for (int rg = 0; rg < 4; ++rg) {
          int r_g = row0 + wr * 64 + mi * 16 + l4 * 4 + rg;
          int c_g = col0 + wc * 64 + nj * 16 + l15;
          OUT[(size_t)r_g * 512 + c_g] = acc[mi][nj][rg];
        }
    return;
  }

  // ---- gemm1 epilogue ----
  const int b = row0 >> 11, srow = row0 & 2047;
  if (by < 8) {
    const int isq = (by < 4);
    const float QS = 0.06375874f;  // 512^-0.5 * log2(e)
    u16* dst = isq ? qo : ko;
#pragma unroll
    for (int mi = 0; mi < 4; ++mi)
#pragma unroll
      for (int nj = 0; nj < 4; ++nj)
#pragma unroll
        for (int rg = 0; rg < 4; ++rg) {
          float v = acc[mi][nj][rg];
          if (isq) v *= QS;
          int s = srow + wr * 64 + mi * 16 + l4 * 4 + rg;
          int ct = ((by & 3) * 128 + wc * 64 + nj * 16 + l15);
          int h = ct >> 6, d = ct & 63;
          dst[(((size_t)b * 8 + h) * 2048 + s) * 64 + d] = f2bf(v);
        }
  } else {
    // v: transpose in TWO 64-col passes (pitch 130), reusing K-loop LDS
    const int vb = by - 8;
#pragma unroll
    for (int h = 0; h < 2; ++h) {
      __syncthreads();
      if (wc == h) {
#pragma unroll
        for (int mi = 0; mi < 4; ++mi)
#pragma unroll
          for (int nj = 0; nj < 4; ++nj)
#pragma unroll
            for (int rg = 0; rg < 4; ++rg) {
              int cl = nj * 16 + l15;
              int s = wr * 64 + mi * 16 + l4 * 4 + rg;
              LDS[cl * 130 + s] = f2bf(acc[mi][nj][rg]);
            }
      }
      __syncthreads();
      const unsigned* LDSw = (const unsigned*)LDS;
      int cl = tid >> 2, sh = tid & 3;
      int ct = vb * 128 + h * 64 + cl;
      int hd = ct >> 6, d = ct & 63;
      size_t o = (((size_t)b * 8 + hd) * 64 + d) * 2048 + srow + sh * 32;
      unsigned wbuf[16];
#pragma unroll
      for (int p = 0; p < 16; ++p) wbuf[p] = LDSw[cl * 65 + sh * 16 + p];
#pragma unroll
      for (int j = 0; j < 4; ++j) {
        uint4 u = {wbuf[j * 4], wbuf[j * 4 + 1], wbuf[j * 4 + 2], wbuf[j * 4 + 3]};
        *(uint4*)(vto + o + j * 8) = u;
      }
    }
  }
}

// ---------------------------------------------------------------------------
// Banded flash attention — R18 version (T4 + swapped QK^T + T5), unchanged.
// ---------------------------------------------------------------------------
__global__ __launch_bounds__(512, 4) void attn_kernel(
    const u16* __restrict__ q, const u16* __restrict__ k,
    const u16* __restrict__ vt, u16* __restrict__ ao) {
  __shared__ u16 KT[3][64 * 64];      // 24 KB
  __shared__ u16 VT[3][64 * 64];      // 24 KB
  __shared__ u16 PT[8][16 * 64];      // 16 KB   PT[w][q][key^swz]
  const int tid = threadIdx.x;
  const int w = tid >> 6, lane = tid & 63;
  const int l15 = lane & 15, l4 = lane >> 4;
  const int bid0 = blockIdx.x;
  const int bid = (bid0 & 7) * 64 + (bid0 >> 3);  // XCD remap (512 % 8 == 0)
  const int qt = bid & 15, hh = (bid >> 4) & 7, b = bid >> 7;
  const size_t base = (size_t)(b * 8 + hh) * 2048 * 64;
  const int q0 = qt * 128 + w * 16;

  s16x8 qf[2];
#pragma unroll
  for (int ks = 0; ks < 2; ++ks)
    qf[ks] = *(const s16x8*)(q + base + (size_t)(q0 + l15) * 64 + ks * 32 + l4 * 8);

  const f32x4 fz = {0.f, 0.f, 0.f, 0.f};
  f32x4 O[4];
  for (int nd = 0; nd < 4; ++nd) O[nd] = fz;
  float l_sum = 0.f;

  const int lrow = lane >> 3, lslot = lane & 7;
  const int swzb = (lslot ^ lrow) << 4;
  const char* pK = (const char*)(k + base) + (w * 8 + lrow) * 128 + swzb;
  const char* pV = (const char*)(vt + base) + (size_t)(w * 8 + lrow) * 4096 + swzb;
  u16* dK = &KT[0][0] + w * 512;
  u16* dV = &VT[0][0] + w * 512;
  u16* phw = &PT[w][0];
  const int pswz = (l15 & 7) << 3;

#define STAGE(c_, b_)                                    \
  do {                                                   \
    gld_lds16(pK + (c_) * 8192, dK + (b_) * 4096);       \
    gld_lds16(pV + (c_) * 128,  dV + (b_) * 4096);       \
  } while (0)

  const int c0 = (2 * qt - 2) < 0 ? 0 : (2 * qt - 2);
  const int c1 = (2 * qt + 3) > 31 ? 31 : (2 * qt + 3);

  STAGE(c0, 0);
  STAGE(c0 + 1, 1);
  asm volatile("s_waitcnt vmcnt(2)" ::: "memory");
  __builtin_amdgcn_sched_barrier(0);
  __builtin_amdgcn_s_barrier();

  for (int c = c0; c <= c1; ++c) {
    const int buf = (c - c0) % 3;
    if (c + 2 <= c1) STAGE(c + 2, (c - c0 + 2) % 3);
    const int kb = c * 64;
    const bool skip = (kb - (q0 + 15) > 128) || (q0 - (kb + 63) > 128);
    if (!skip) {
      f32x4 S[4];
      for (int nj = 0; nj < 4; ++nj) S[nj] = fz;
      __builtin_amdgcn_s_setprio(1);
#pragma unroll
      for (int nj = 0; nj < 4; ++nj) {
        const int r = nj * 16 + l15;
#pragma unroll
        for (int ks = 0; ks < 2; ++ks) {
          const int sl = (ks * 4 + l4) ^ (r & 7);
          s16x8 kf = *(const s16x8*)&KT[buf][r * 64 + sl * 8];
          S[nj] = MFMA16(kf, qf[ks], S[nj]);
        }
      }
      __builtin_amdgcn_s_setprio(0);
      const bool needmask = (kb + 63 - q0 > 128) || (q0 + 15 - kb > 128);
      const int qrow = q0 + l15;
#pragma unroll
      for (int nj = 0; nj < 4; ++nj) {
        float p[4];
#pragma unroll
        for (int rg = 0; rg < 4; ++rg) {
          const int key = kb + nj * 16 + l4 * 4 + rg;
          float pp = exp2f(S[nj][rg]);
          if (needmask) {
            int dd = key - qrow;
            if (dd > 128 || dd < -128) pp = 0.f;
          }
          l_sum += pp;
          p[rg] = pp;
        }
        unsigned w0 = (unsigned)f2bf(p[0]) | ((unsigned)f2bf(p[1]) << 16);
        unsigned w1 = (unsigned)f2bf(p[2]) | ((unsigned)f2bf(p[3]) << 16);
        u64 pk = ((u64)w1 << 32) | (u64)w0;
        const int kbase = (nj * 16 + l4 * 4) ^ pswz;
        *(u64*)&phw[l15 * 64 + kbase] = pk;
      }
      __builtin_amdgcn_s_setprio(1);
#pragma unroll
      for (int ksp = 0; ksp < 2; ++ksp) {
        const int kbase = (ksp * 32 + l4 * 8) ^ pswz;
        s16x8 pa = *(const s16x8*)&phw[l15 * 64 + kbase];
#pragma unroll
        for (int nd = 0; nd < 4; ++nd) {
          const int r = nd * 16 + l15;
          const int sl = (ksp * 4 + l4) ^ (r & 7);
          s16x8 vf = *(const s16x8*)&VT[buf][r * 64 + sl * 8];
          O[nd] = MFMA16(pa, vf, O[nd]);
        }
      }
      __builtin_amdgcn_s_setprio(0);
    }
    if (c < c1) {
      if (c + 2 <= c1) {
        asm volatile("s_waitcnt vmcnt(2)" ::: "memory");
      } else {
        asm volatile("s_waitcnt vmcnt(0)" ::: "memory");
      }
      __builtin_amdgcn_sched_barrier(0);
      __builtin_amdgcn_s_barrier();
    }
  }
#undef STAGE

  l_sum += __shfl_xor(l_sum, 16);
  l_sum += __shfl_xor(l_sum, 32);
  float linv = 1.0f / l_sum;
#pragma unroll
  for (int rg = 0; rg < 4; ++rg) {
    const float inv = __shfl(linv, l4 * 4 + rg);
    const int s_g = q0 + l4 * 4 + rg;
#pragma unroll
    for (int nd = 0; nd < 4; ++nd) {
      float v = O[nd][rg] * inv;
      const int c_g = hh * 64 + nd * 16 + l15;
      ao[((size_t)b * 2048 + s_g) * 512 + c_g] = f2bf(v);
    }
  }
}

// ---------------------------------------------------------------------------
extern "C" void kernel_launch(void* const* d_in, const int* in_sizes, int n_in,
                              void* d_out, int out_size, void* d_ws, size_t ws_size,
                              hipStream_t stream) {
  const float* x = (const float*)d_in[0];      // [4,2048,512]
  const float* wqkv = (const float*)d_in[1];   // [512,1536]
  const float* wproj = (const float*)d_in[2];  // [512,512]
  float* out = (float*)d_out;                  // [4,2048,512]

  char* ws = (char*)d_ws;
  size_t off = 0;
  auto alloc = [&](size_t bytes) {
    void* p = ws + off;
    off += (bytes + 255) & ~(size_t)255;
    return p;
  };
  const size_t E = (size_t)4 * 8 * 2048 * 64;
  u16* Xb  = (u16*)alloc(E * 2);
  u16* qb  = (u16*)alloc(E * 2);
  u16* kb  = (u16*)alloc(E * 2);
  u16* vtb = (u16*)alloc(E * 2);
  u16* aob = (u16*)alloc(E * 2);
  u16* wqT = (u16*)alloc((size_t)1536 * 512 * 2);
  u16* wpT = (u16*)alloc((size_t)512 * 512 * 2);

  prep<<<dim3(2560), dim3(256), 0, stream>>>(x, wqkv, wproj, Xb, wqT, wpT);
  gemm_bf16<1, 12><<<dim3(768), dim3(256), 0, stream>>>(Xb, wqT, nullptr, qb, kb, vtb);
  attn_kernel<<<dim3(512), dim3(512), 0, stream>>>(qb, kb, vtb, aob);
  gemm_bf16<0, 4><<<dim3(256), dim3(256), 0, stream>>>(aob, wpT, out, nullptr, nullptr, nullptr);
}